// Round 1
// baseline (528.180 us; speedup 1.0000x reference)
//
#include <hip/hip_runtime.h>
#include <math.h>

#define D 128
#define NGRAPH 16

// ---------------------------------------------------------------------------
// Stage 1: fused projections  x_m = X @ W_m + b_m  for m=1..4
// grid.x = ceil(N/64), grid.y = 8  (matrix m = y>>1, colBase = (y&1)*64)
// 256 threads; per-thread 4x4 micro-tile; X^T tile staged in LDS.
// ---------------------------------------------------------------------------
__global__ __launch_bounds__(256) void proj_kernel(
    const float* __restrict__ X,
    const float* __restrict__ W1, const float* __restrict__ b1,
    const float* __restrict__ W2, const float* __restrict__ b2,
    const float* __restrict__ W3, const float* __restrict__ b3,
    const float* __restrict__ W4, const float* __restrict__ b4,
    float* __restrict__ x1, float* __restrict__ x2,
    float* __restrict__ x3, float* __restrict__ x4,
    int N)
{
    __shared__ float XsT[128][68];   // [k][row], pad to 68 to break bank stride

    const float* Ws[4]   = {W1, W2, W3, W4};
    const float* bs[4]   = {b1, b2, b3, b4};
    float*       outs[4] = {x1, x2, x3, x4};

    const int m        = blockIdx.y >> 1;
    const int colBase  = (blockIdx.y & 1) * 64;
    const float* W     = Ws[m];
    const float* bias  = bs[m];
    float*       Out   = outs[m];

    const int nodeBase = blockIdx.x * 64;
    const int tid      = threadIdx.x;

    // stage X^T (64 rows x 128 k) into LDS
    {
        int rd_r  = tid >> 2;          // 0..63
        int rd_k0 = (tid & 3) * 32;    // 0,32,64,96
        int row   = nodeBase + rd_r;
        if (row >= N) row = N - 1;     // clamp (stores are guarded)
        const float* src = X + (size_t)row * D + rd_k0;
        #pragma unroll
        for (int kk = 0; kk < 32; kk += 4) {
            float4 v = *(const float4*)(src + kk);
            XsT[rd_k0 + kk + 0][rd_r] = v.x;
            XsT[rd_k0 + kk + 1][rd_r] = v.y;
            XsT[rd_k0 + kk + 2][rd_r] = v.z;
            XsT[rd_k0 + kk + 3][rd_r] = v.w;
        }
    }
    __syncthreads();

    const int tx = tid & 15;          // col group
    const int ty = tid >> 4;          // row group
    const int c0 = colBase + tx * 4;  // global col in [0,128)
    const int r0 = ty * 4;            // local row in [0,64)

    float acc[4][4] = {};

    #pragma unroll 4
    for (int k = 0; k < 128; ++k) {
        float4 a4 = *(const float4*)&XsT[k][r0];
        float4 b4 = *(const float4*)&W[k * D + c0];
        float av[4] = {a4.x, a4.y, a4.z, a4.w};
        float bv[4] = {b4.x, b4.y, b4.z, b4.w};
        #pragma unroll
        for (int i = 0; i < 4; ++i)
            #pragma unroll
            for (int j = 0; j < 4; ++j)
                acc[i][j] = fmaf(av[i], bv[j], acc[i][j]);
    }

    float4 bias4 = *(const float4*)&bias[c0];
    #pragma unroll
    for (int i = 0; i < 4; ++i) {
        int row = nodeBase + r0 + i;
        if (row < N) {
            float4 o;
            o.x = acc[i][0] + bias4.x;
            o.y = acc[i][1] + bias4.y;
            o.z = acc[i][2] + bias4.z;
            o.w = acc[i][3] + bias4.w;
            *(float4*)&Out[(size_t)row * D + c0] = o;
        }
    }
}

// ---------------------------------------------------------------------------
// Stage 2: CSR build by dst
// ---------------------------------------------------------------------------
__global__ void count_kernel(const int* __restrict__ dstIdx, int* __restrict__ cnt, int E)
{
    int e = blockIdx.x * 256 + threadIdx.x;
    if (e < E) atomicAdd(&cnt[dstIdx[e]], 1);
}

__global__ __launch_bounds__(256) void scan1(const int* __restrict__ cnt,
                                             int* __restrict__ row_off,
                                             int* __restrict__ bsum, int N)
{
    __shared__ int s[256];
    int tid = threadIdx.x;
    int i0  = blockIdx.x * 1024 + tid * 4;
    int v[4];
    #pragma unroll
    for (int j = 0; j < 4; ++j) v[j] = (i0 + j < N) ? cnt[i0 + j] : 0;
    int t = v[0] + v[1] + v[2] + v[3];
    s[tid] = t;
    __syncthreads();
    for (int off = 1; off < 256; off <<= 1) {
        int y = 0;
        if (tid >= off) y = s[tid - off];
        __syncthreads();
        s[tid] += y;
        __syncthreads();
    }
    int run = s[tid] - t;  // exclusive prefix for this thread
    #pragma unroll
    for (int j = 0; j < 4; ++j) {
        if (i0 + j < N) row_off[i0 + j] = run;
        run += v[j];
    }
    if (tid == 255) bsum[blockIdx.x] = s[255];
}

// exclusive scan of up to 128 block sums, one wave
__global__ void scan2(int* __restrict__ bsum, int nb)
{
    int lane = threadIdx.x;  // blockDim = 64
    int a = (lane < nb) ? bsum[lane] : 0;
    int b = (64 + lane < nb) ? bsum[64 + lane] : 0;
    int xa = a;
    #pragma unroll
    for (int off = 1; off < 64; off <<= 1) {
        int y = __shfl_up(xa, off);
        if (lane >= off) xa += y;
    }
    int totA = __shfl(xa, 63);
    int xb = b;
    #pragma unroll
    for (int off = 1; off < 64; off <<= 1) {
        int y = __shfl_up(xb, off);
        if (lane >= off) xb += y;
    }
    if (lane < nb) bsum[lane] = xa - a;
    if (64 + lane < nb) bsum[64 + lane] = totA + xb - b;
}

__global__ void scan3(int* __restrict__ row_off, const int* __restrict__ bsum, int N)
{
    int i = blockIdx.x * 256 + threadIdx.x;
    if (i < N) row_off[i] += bsum[i >> 10];
}

__global__ void fill_kernel(const int* __restrict__ dstIdx,
                            const int* __restrict__ row_off,
                            int* __restrict__ cur,
                            int* __restrict__ edge_ids, int E)
{
    int e = blockIdx.x * 256 + threadIdx.x;
    if (e < E) {
        int d = dstIdx[e];
        int p = atomicAdd(&cur[d], 1);
        edge_ids[row_off[d] + p] = e;
    }
}

// ---------------------------------------------------------------------------
// Stage 3: fused per-dst-node: scores -> online segment softmax -> alpha*x2
// aggregation -> + x1 -> node_out (written in place over x1).
// One wave per node, 4 waves/block.
//   score(e) = (x3[dst].x4[src] + attr[e]*p + q) / sqrt(128)
//   p = x3[dst].W5row, q = x3[dst].b5
// ---------------------------------------------------------------------------
__global__ __launch_bounds__(256) void node_kernel(
    float* x1,                         // read x1, write node_out (same rows)
    const float* __restrict__ x2,
    const float* __restrict__ x3,
    const float* __restrict__ x4,
    const int* __restrict__ srcIdx,
    const float* __restrict__ eattr,
    const float* __restrict__ W5,
    const float* __restrict__ b5,
    const int* __restrict__ row_off,
    const int* __restrict__ cnt,
    const int* __restrict__ edge_ids,
    int N)
{
    int n    = blockIdx.x * 4 + (threadIdx.x >> 6);
    int lane = threadIdx.x & 63;
    if (n >= N) return;

    const float2 a3 = *(const float2*)(x3 + (size_t)n * D + lane * 2);
    const float2 w5 = *(const float2*)(W5 + lane * 2);
    const float2 v5 = *(const float2*)(b5 + lane * 2);

    float p = a3.x * w5.x + a3.y * w5.y;
    float q = a3.x * v5.x + a3.y * v5.y;
    #pragma unroll
    for (int off = 32; off; off >>= 1) {
        p += __shfl_xor(p, off);
        q += __shfl_xor(q, off);
    }

    const int start = row_off[n];
    const int deg   = cnt[n];
    const float inv_sqrt_d = 0.08838834764831845f;  // 1/sqrt(128)

    float mrun = -INFINITY, z = 0.f;
    float accx = 0.f, accy = 0.f;

    for (int i = 0; i < deg; ++i) {
        int   e    = edge_ids[start + i];
        int   src  = srcIdx[e];
        float attr = eattr[e];

        const float2 b4 = *(const float2*)(x4 + (size_t)src * D + lane * 2);
        float d = a3.x * b4.x + a3.y * b4.y;
        #pragma unroll
        for (int off = 32; off; off >>= 1) d += __shfl_xor(d, off);

        float score = (d + attr * p + q) * inv_sqrt_d;
        float mn = fmaxf(mrun, score);
        float sc = __expf(mrun - mn);     // 0 on first iter (mrun = -inf)
        float w  = __expf(score - mn);
        z = z * sc + w;

        const float2 v = *(const float2*)(x2 + (size_t)src * D + lane * 2);
        accx = accx * sc + w * v.x;
        accy = accy * sc + w * v.y;
        mrun = mn;
    }

    float2 o = *(const float2*)(x1 + (size_t)n * D + lane * 2);
    if (deg > 0) {
        float inv = 1.f / z;
        o.x += accx * inv;
        o.y += accy * inv;
    }
    *(float2*)(x1 + (size_t)n * D + lane * 2) = o;
}

// ---------------------------------------------------------------------------
// Stage 4: global mean pool. batch is sorted -> per-thread running register
// accumulator per graph, flush on graph change (few global atomics).
// block = 256 threads = 2 nodes x 128 cols per step, contiguous chunk/block.
// ---------------------------------------------------------------------------
__global__ __launch_bounds__(256) void pool_kernel(
    const float* __restrict__ node_out,
    const int* __restrict__ batch,
    float* __restrict__ pooled,
    float* __restrict__ cntf,
    int N)
{
    int c   = threadIdx.x & 127;
    int sub = threadIdx.x >> 7;  // 0..1
    int nodesPerBlock = (N + gridDim.x - 1) / gridDim.x;
    int startN = blockIdx.x * nodesPerBlock;
    int endN   = min(startN + nodesPerBlock, N);

    float acc = 0.f, cct = 0.f;
    int gcur = -1;
    for (int n = startN + sub; n < endN; n += 2) {
        int g = batch[n];
        float v = node_out[(size_t)n * D + c];
        if (g != gcur) {
            if (gcur >= 0) {
                atomicAdd(&pooled[gcur * D + c], acc);
                if (c == 0) atomicAdd(&cntf[gcur], cct);
            }
            gcur = g; acc = 0.f; cct = 0.f;
        }
        acc += v; cct += 1.f;
    }
    if (gcur >= 0) {
        atomicAdd(&pooled[gcur * D + c], acc);
        if (c == 0) atomicAdd(&cntf[gcur], cct);
    }
}

__global__ void final_kernel(const float* __restrict__ pooled,
                             const float* __restrict__ cntf,
                             float* __restrict__ out)
{
    int i = blockIdx.x * 256 + threadIdx.x;
    if (i < NGRAPH * D) {
        float cval = cntf[i >> 7];
        out[i] = pooled[i] / fmaxf(cval, 1.f);
    }
}

// ---------------------------------------------------------------------------
extern "C" void kernel_launch(void* const* d_in, const int* in_sizes, int n_in,
                              void* d_out, int out_size, void* d_ws, size_t ws_size,
                              hipStream_t stream)
{
    const float* x     = (const float*)d_in[0];
    const int*   eidx  = (const int*)d_in[1];   // [2,E]: src = eidx[e], dst = eidx[E+e]
    const float* eattr = (const float*)d_in[2];
    const int*   batch = (const int*)d_in[3];
    const float* W1 = (const float*)d_in[4];  const float* b1 = (const float*)d_in[5];
    const float* W2 = (const float*)d_in[6];  const float* b2 = (const float*)d_in[7];
    const float* W3 = (const float*)d_in[8];  const float* b3 = (const float*)d_in[9];
    const float* W4 = (const float*)d_in[10]; const float* b4 = (const float*)d_in[11];
    const float* W5 = (const float*)d_in[12]; const float* b5 = (const float*)d_in[13];
    float* out = (float*)d_out;

    const int N = in_sizes[0] / D;
    const int E = in_sizes[1] / 2;

    // workspace layout
    char* ws = (char*)d_ws;
    size_t NB = (size_t)N * D * sizeof(float);
    float* x1 = (float*)(ws + 0 * NB);   // also node_out (in place)
    float* x2 = (float*)(ws + 1 * NB);
    float* x3 = (float*)(ws + 2 * NB);
    float* x4 = (float*)(ws + 3 * NB);
    int* cnt      = (int*)(ws + 4 * NB);
    int* row_off  = cnt + N;
    int* cur      = row_off + N;
    int* edge_ids = cur + N;
    int* bsum     = edge_ids + E;
    float* pooled = (float*)(bsum + 256);
    float* cntf   = pooled + NGRAPH * D;

    hipMemsetAsync(cnt, 0, (size_t)N * sizeof(int), stream);
    hipMemsetAsync(cur, 0, (size_t)N * sizeof(int), stream);
    hipMemsetAsync(pooled, 0, (size_t)(NGRAPH * D + NGRAPH) * sizeof(float), stream);

    dim3 pg((N + 63) / 64, 8);
    proj_kernel<<<pg, 256, 0, stream>>>(x, W1, b1, W2, b2, W3, b3, W4, b4,
                                        x1, x2, x3, x4, N);

    count_kernel<<<(E + 255) / 256, 256, 0, stream>>>(eidx + E, cnt, E);
    int nb = (N + 1023) / 1024;
    scan1<<<nb, 256, 0, stream>>>(cnt, row_off, bsum, N);
    scan2<<<1, 64, 0, stream>>>(bsum, nb);
    scan3<<<(N + 255) / 256, 256, 0, stream>>>(row_off, bsum, N);
    fill_kernel<<<(E + 255) / 256, 256, 0, stream>>>(eidx + E, row_off, cur, edge_ids, E);

    node_kernel<<<(N + 3) / 4, 256, 0, stream>>>(x1, x2, x3, x4, eidx, eattr,
                                                 W5, b5, row_off, cnt, edge_ids, N);

    pool_kernel<<<256, 256, 0, stream>>>(x1, batch, pooled, cntf, N);
    final_kernel<<<(NGRAPH * D + 255) / 256, 256, 0, stream>>>(pooled, cntf, out);
}

// Round 2
// 375.014 us; speedup vs baseline: 1.4084x; 1.4084x over previous
//
#include <hip/hip_runtime.h>
#include <hip/hip_bf16.h>
#include <math.h>

#define D 128
#define NGRAPH 16

typedef __attribute__((ext_vector_type(8))) short bf16x8;   // 8 bf16 (4 VGPRs)
typedef __attribute__((ext_vector_type(4))) float f32x4;    // MFMA C/D

// ---------------------------------------------------------------------------
// Stage 0: convert W1..W4 to bf16, transposed to [m][col][k] (k contiguous)
// ---------------------------------------------------------------------------
__global__ void wconv_kernel(const float* __restrict__ W1, const float* __restrict__ W2,
                             const float* __restrict__ W3, const float* __restrict__ W4,
                             __hip_bfloat16* __restrict__ Wbt)
{
    int id = blockIdx.x * 256 + threadIdx.x;      // 4*128*128 = 65536
    if (id >= 4 * D * D) return;
    int mm  = id >> 14;
    int rem = id & 16383;
    int c   = rem >> 7;
    int k   = rem & 127;
    const float* Wm = (mm == 0) ? W1 : (mm == 1) ? W2 : (mm == 2) ? W3 : W4;
    Wbt[id] = __float2bfloat16(Wm[k * D + c]);
}

// ---------------------------------------------------------------------------
// Stage 1: projections via bf16 MFMA.
// grid = (ceil(N/128), 4); 256 threads = 4 waves in 2x2; tile 128 rows x 128 cols.
// Xs: [row][k] bf16 padded to 136 (row stride 272B -> 2-way LDS = free).
// Ws: [col][k] bf16 padded likewise (B^T layout, k contiguous for b128 reads).
// MFMA 16x16x32 bf16: A row=lane&15, k=(lane>>4)*8+j ; B col=lane&15, same k;
// D col=lane&15, row=(lane>>4)*4+reg  [measured m89].
// ---------------------------------------------------------------------------
__global__ __launch_bounds__(256) void proj2_kernel(
    const float* __restrict__ X,
    const __hip_bfloat16* __restrict__ Wbt,  // [4][128 col][128 k]
    const float* __restrict__ b1, const float* __restrict__ b2,
    const float* __restrict__ b3, const float* __restrict__ b4,
    float* __restrict__ x1, float* __restrict__ x2,
    float* __restrict__ x3, float* __restrict__ x4,
    int N)
{
    __shared__ __hip_bfloat16 Xs[128][136];
    __shared__ __hip_bfloat16 Ws[128][136];

    const int m = blockIdx.y;
    const float* bias = (m == 0) ? b1 : (m == 1) ? b2 : (m == 2) ? b3 : b4;
    float*       Out  = (m == 0) ? x1 : (m == 1) ? x2 : (m == 2) ? x3 : x4;

    const int nodeBase = blockIdx.x * 128;
    const int tid      = threadIdx.x;

    // ---- stage X (fp32 -> bf16) ----
    {
        int r  = tid >> 1;            // 0..127
        int k0 = (tid & 1) * 64;
        int row = nodeBase + r;
        if (row >= N) row = N - 1;    // clamp; stores are guarded
        const float* src = X + (size_t)row * D + k0;
        #pragma unroll
        for (int i = 0; i < 8; ++i) {
            float4 u = *(const float4*)(src + i * 8);
            float4 v = *(const float4*)(src + i * 8 + 4);
            __hip_bfloat16 h[8];
            h[0] = __float2bfloat16(u.x); h[1] = __float2bfloat16(u.y);
            h[2] = __float2bfloat16(u.z); h[3] = __float2bfloat16(u.w);
            h[4] = __float2bfloat16(v.x); h[5] = __float2bfloat16(v.y);
            h[6] = __float2bfloat16(v.z); h[7] = __float2bfloat16(v.w);
            *(uint4*)&Xs[r][k0 + i * 8] = *(const uint4*)h;
        }
    }
    // ---- stage W (bf16 copy) ----
    {
        int c  = tid >> 1;            // 0..127
        int k0 = (tid & 1) * 64;
        const uint4* src = (const uint4*)(Wbt + ((size_t)m * D + c) * D + k0);
        uint4* dst = (uint4*)&Ws[c][k0];
        #pragma unroll
        for (int i = 0; i < 8; ++i) dst[i] = src[i];
    }
    __syncthreads();

    const int wv   = tid >> 6;        // 0..3
    const int lane = tid & 63;
    const int wr   = (wv >> 1) * 64;  // wave row base
    const int wc   = (wv & 1) * 64;   // wave col base
    const int fr   = lane & 15;
    const int fq   = lane >> 4;

    f32x4 acc[4][4] = {};             // [mf][nf]

    #pragma unroll
    for (int kk = 0; kk < 4; ++kk) {
        bf16x8 a[4], b[4];
        #pragma unroll
        for (int mf = 0; mf < 4; ++mf)
            a[mf] = *(const bf16x8*)&Xs[wr + mf * 16 + fr][kk * 32 + fq * 8];
        #pragma unroll
        for (int nf = 0; nf < 4; ++nf)
            b[nf] = *(const bf16x8*)&Ws[wc + nf * 16 + fr][kk * 32 + fq * 8];
        #pragma unroll
        for (int mf = 0; mf < 4; ++mf)
            #pragma unroll
            for (int nf = 0; nf < 4; ++nf)
                acc[mf][nf] = __builtin_amdgcn_mfma_f32_16x16x32_bf16(
                    a[mf], b[nf], acc[mf][nf], 0, 0, 0);
    }

    // ---- epilogue: add bias, store fp32 ----
    #pragma unroll
    for (int mf = 0; mf < 4; ++mf) {
        #pragma unroll
        for (int nf = 0; nf < 4; ++nf) {
            int col = wc + nf * 16 + fr;
            float bv = bias[col];
            #pragma unroll
            for (int j = 0; j < 4; ++j) {
                int row = nodeBase + wr + mf * 16 + fq * 4 + j;
                if (row < N)
                    Out[(size_t)row * D + col] = acc[mf][nf][j] + bv;
            }
        }
    }
}

// ---------------------------------------------------------------------------
// Stage 2: CSR build by dst
// ---------------------------------------------------------------------------
__global__ void count_kernel(const int* __restrict__ dstIdx, int* __restrict__ cnt, int E)
{
    int e = blockIdx.x * 256 + threadIdx.x;
    if (e < E) atomicAdd(&cnt[dstIdx[e]], 1);
}

__global__ __launch_bounds__(256) void scan1(const int* __restrict__ cnt,
                                             int* __restrict__ row_off,
                                             int* __restrict__ bsum, int N)
{
    __shared__ int s[256];
    int tid = threadIdx.x;
    int i0  = blockIdx.x * 1024 + tid * 4;
    int v[4];
    #pragma unroll
    for (int j = 0; j < 4; ++j) v[j] = (i0 + j < N) ? cnt[i0 + j] : 0;
    int t = v[0] + v[1] + v[2] + v[3];
    s[tid] = t;
    __syncthreads();
    for (int off = 1; off < 256; off <<= 1) {
        int y = 0;
        if (tid >= off) y = s[tid - off];
        __syncthreads();
        s[tid] += y;
        __syncthreads();
    }
    int run = s[tid] - t;  // exclusive prefix for this thread
    #pragma unroll
    for (int j = 0; j < 4; ++j) {
        if (i0 + j < N) row_off[i0 + j] = run;
        run += v[j];
    }
    if (tid == 255) bsum[blockIdx.x] = s[255];
}

__global__ void scan2(int* __restrict__ bsum, int nb)
{
    int lane = threadIdx.x;  // blockDim = 64
    int a = (lane < nb) ? bsum[lane] : 0;
    int b = (64 + lane < nb) ? bsum[64 + lane] : 0;
    int xa = a;
    #pragma unroll
    for (int off = 1; off < 64; off <<= 1) {
        int y = __shfl_up(xa, off);
        if (lane >= off) xa += y;
    }
    int totA = __shfl(xa, 63);
    int xb = b;
    #pragma unroll
    for (int off = 1; off < 64; off <<= 1) {
        int y = __shfl_up(xb, off);
        if (lane >= off) xb += y;
    }
    if (lane < nb) bsum[lane] = xa - a;
    if (64 + lane < nb) bsum[64 + lane] = totA + xb - b;
}

__global__ void scan3(int* __restrict__ row_off, const int* __restrict__ bsum, int N)
{
    int i = blockIdx.x * 256 + threadIdx.x;
    if (i < N) row_off[i] += bsum[i >> 10];
}

__global__ void fill_kernel(const int* __restrict__ dstIdx,
                            const int* __restrict__ row_off,
                            int* __restrict__ cur,
                            int* __restrict__ edge_ids, int E)
{
    int e = blockIdx.x * 256 + threadIdx.x;
    if (e < E) {
        int d = dstIdx[e];
        int p = atomicAdd(&cur[d], 1);
        edge_ids[row_off[d] + p] = e;
    }
}

// ---------------------------------------------------------------------------
// Stage 3: fused per-dst-node attention + aggregation (one wave per node).
// ---------------------------------------------------------------------------
__global__ __launch_bounds__(256) void node_kernel(
    float* x1,                         // read x1, write node_out (in place)
    const float* __restrict__ x2,
    const float* __restrict__ x3,
    const float* __restrict__ x4,
    const int* __restrict__ srcIdx,
    const float* __restrict__ eattr,
    const float* __restrict__ W5,
    const float* __restrict__ b5,
    const int* __restrict__ row_off,
    const int* __restrict__ cnt,
    const int* __restrict__ edge_ids,
    int N)
{
    int n    = blockIdx.x * 4 + (threadIdx.x >> 6);
    int lane = threadIdx.x & 63;
    if (n >= N) return;

    const float2 a3 = *(const float2*)(x3 + (size_t)n * D + lane * 2);
    const float2 w5 = *(const float2*)(W5 + lane * 2);
    const float2 v5 = *(const float2*)(b5 + lane * 2);

    float p = a3.x * w5.x + a3.y * w5.y;
    float q = a3.x * v5.x + a3.y * v5.y;
    #pragma unroll
    for (int off = 32; off; off >>= 1) {
        p += __shfl_xor(p, off);
        q += __shfl_xor(q, off);
    }

    const int start = row_off[n];
    const int deg   = cnt[n];
    const float inv_sqrt_d = 0.08838834764831845f;  // 1/sqrt(128)

    float mrun = -INFINITY, z = 0.f;
    float accx = 0.f, accy = 0.f;

    for (int i = 0; i < deg; ++i) {
        int   e    = edge_ids[start + i];
        int   src  = srcIdx[e];
        float attr = eattr[e];

        const float2 b4 = *(const float2*)(x4 + (size_t)src * D + lane * 2);
        float d = a3.x * b4.x + a3.y * b4.y;
        #pragma unroll
        for (int off = 32; off; off >>= 1) d += __shfl_xor(d, off);

        float score = (d + attr * p + q) * inv_sqrt_d;
        float mn = fmaxf(mrun, score);
        float sc = __expf(mrun - mn);     // 0 on first iter
        float w  = __expf(score - mn);
        z = z * sc + w;

        const float2 v = *(const float2*)(x2 + (size_t)src * D + lane * 2);
        accx = accx * sc + w * v.x;
        accy = accy * sc + w * v.y;
        mrun = mn;
    }

    float2 o = *(const float2*)(x1 + (size_t)n * D + lane * 2);
    if (deg > 0) {
        float inv = 1.f / z;
        o.x += accx * inv;
        o.y += accy * inv;
    }
    *(float2*)(x1 + (size_t)n * D + lane * 2) = o;
}

// ---------------------------------------------------------------------------
// Stage 4: global mean pool (batch sorted -> register accumulate, few atomics)
// ---------------------------------------------------------------------------
__global__ __launch_bounds__(256) void pool_kernel(
    const float* __restrict__ node_out,
    const int* __restrict__ batch,
    float* __restrict__ pooled,
    float* __restrict__ cntf,
    int N)
{
    int c   = threadIdx.x & 127;
    int sub = threadIdx.x >> 7;  // 0..1
    int nodesPerBlock = (N + gridDim.x - 1) / gridDim.x;
    int startN = blockIdx.x * nodesPerBlock;
    int endN   = min(startN + nodesPerBlock, N);

    float acc = 0.f, cct = 0.f;
    int gcur = -1;
    for (int n = startN + sub; n < endN; n += 2) {
        int g = batch[n];
        float v = node_out[(size_t)n * D + c];
        if (g != gcur) {
            if (gcur >= 0) {
                atomicAdd(&pooled[gcur * D + c], acc);
                if (c == 0) atomicAdd(&cntf[gcur], cct);
            }
            gcur = g; acc = 0.f; cct = 0.f;
        }
        acc += v; cct += 1.f;
    }
    if (gcur >= 0) {
        atomicAdd(&pooled[gcur * D + c], acc);
        if (c == 0) atomicAdd(&cntf[gcur], cct);
    }
}

__global__ void final_kernel(const float* __restrict__ pooled,
                             const float* __restrict__ cntf,
                             float* __restrict__ out)
{
    int i = blockIdx.x * 256 + threadIdx.x;
    if (i < NGRAPH * D) {
        float cval = cntf[i >> 7];
        out[i] = pooled[i] / fmaxf(cval, 1.f);
    }
}

// ---------------------------------------------------------------------------
extern "C" void kernel_launch(void* const* d_in, const int* in_sizes, int n_in,
                              void* d_out, int out_size, void* d_ws, size_t ws_size,
                              hipStream_t stream)
{
    const float* x     = (const float*)d_in[0];
    const int*   eidx  = (const int*)d_in[1];   // [2,E]: src = eidx[e], dst = eidx[E+e]
    const float* eattr = (const float*)d_in[2];
    const int*   batch = (const int*)d_in[3];
    const float* W1 = (const float*)d_in[4];  const float* b1 = (const float*)d_in[5];
    const float* W2 = (const float*)d_in[6];  const float* b2 = (const float*)d_in[7];
    const float* W3 = (const float*)d_in[8];  const float* b3 = (const float*)d_in[9];
    const float* W4 = (const float*)d_in[10]; const float* b4 = (const float*)d_in[11];
    const float* W5 = (const float*)d_in[12]; const float* b5 = (const float*)d_in[13];
    float* out = (float*)d_out;

    const int N = in_sizes[0] / D;
    const int E = in_sizes[1] / 2;

    // workspace layout
    char* ws = (char*)d_ws;
    size_t NB = (size_t)N * D * sizeof(float);
    float* x1 = (float*)(ws + 0 * NB);   // also node_out (in place)
    float* x2 = (float*)(ws + 1 * NB);
    float* x3 = (float*)(ws + 2 * NB);
    float* x4 = (float*)(ws + 3 * NB);
    int* cnt      = (int*)(ws + 4 * NB);
    int* row_off  = cnt + N;
    int* cur      = row_off + N;
    int* edge_ids = cur + N;
    int* bsum     = edge_ids + E;
    float* pooled = (float*)(bsum + 256);
    float* cntf   = pooled + NGRAPH * D;
    __hip_bfloat16* Wbt = (__hip_bfloat16*)(cntf + NGRAPH);

    hipMemsetAsync(cnt, 0, (size_t)N * sizeof(int), stream);
    hipMemsetAsync(cur, 0, (size_t)N * sizeof(int), stream);
    hipMemsetAsync(pooled, 0, (size_t)(NGRAPH * D + NGRAPH) * sizeof(float), stream);

    wconv_kernel<<<(4 * D * D + 255) / 256, 256, 0, stream>>>(W1, W2, W3, W4, Wbt);

    dim3 pg((N + 127) / 128, 4);
    proj2_kernel<<<pg, 256, 0, stream>>>(x, Wbt, b1, b2, b3, b4,
                                         x1, x2, x3, x4, N);

    count_kernel<<<(E + 255) / 256, 256, 0, stream>>>(eidx + E, cnt, E);
    int nb = (N + 1023) / 1024;
    scan1<<<nb, 256, 0, stream>>>(cnt, row_off, bsum, N);
    scan2<<<1, 64, 0, stream>>>(bsum, nb);
    scan3<<<(N + 255) / 256, 256, 0, stream>>>(row_off, bsum, N);
    fill_kernel<<<(E + 255) / 256, 256, 0, stream>>>(eidx + E, row_off, cur, edge_ids, E);

    node_kernel<<<(N + 3) / 4, 256, 0, stream>>>(x1, x2, x3, x4, eidx, eattr,
                                                 W5, b5, row_off, cnt, edge_ids, N);

    pool_kernel<<<256, 256, 0, stream>>>(x1, batch, pooled, cntf, N);
    final_kernel<<<(NGRAPH * D + 255) / 256, 256, 0, stream>>>(pooled, cntf, out);
}

// Round 3
// 304.327 us; speedup vs baseline: 1.7356x; 1.2323x over previous
//
#include <hip/hip_runtime.h>
#include <hip/hip_bf16.h>
#include <math.h>

#define D 128
#define NGRAPH 16

typedef __attribute__((ext_vector_type(8))) short bf16x8;   // 8 bf16 (4 VGPRs)
typedef __attribute__((ext_vector_type(4))) float f32x4;    // MFMA C/D

// low-indexed / high-indexed bf16 of a packed pair -> f32
__device__ __forceinline__ float bflo(unsigned u) {
    union { unsigned i; float f; } v; v.i = u << 16; return v.f;
}
__device__ __forceinline__ float bfhi(unsigned u) {
    union { unsigned i; float f; } v; v.i = u & 0xffff0000u; return v.f;
}

// ---------------------------------------------------------------------------
// Stage 0: convert W1..W4 to bf16, transposed to [m][col][k] (k contiguous)
// ---------------------------------------------------------------------------
__global__ void wconv_kernel(const float* __restrict__ W1, const float* __restrict__ W2,
                             const float* __restrict__ W3, const float* __restrict__ W4,
                             __hip_bfloat16* __restrict__ Wbt)
{
    int id = blockIdx.x * 256 + threadIdx.x;      // 4*128*128 = 65536
    if (id >= 4 * D * D) return;
    int mm  = id >> 14;
    int rem = id & 16383;
    int c   = rem >> 7;
    int k   = rem & 127;
    const float* Wm = (mm == 0) ? W1 : (mm == 1) ? W2 : (mm == 2) ? W3 : W4;
    Wbt[id] = __float2bfloat16(Wm[k * D + c]);
}

// ---------------------------------------------------------------------------
// Stage 1: ALL FOUR projections in one kernel via bf16 MFMA.
// grid = ceil(N/128); 256 threads = 4 waves (2x2); X tile staged once as bf16,
// A-frags cached in VGPRs across the m-loop; B-frags read from L2-resident Wbt.
// Outputs: m=0 -> x1 (fp32), m=2 -> x3 (fp32),
//          m=3 -> g[node][0..127]   (x4, bf16),
//          m=1 -> g[node][128..255] (x2, bf16).
// MFMA 16x16x32 bf16 C/D map: col=lane&15, row=(lane>>4)*4+reg  [m89].
// ---------------------------------------------------------------------------
__global__ __launch_bounds__(256) void proj3_kernel(
    const float* __restrict__ X,
    const __hip_bfloat16* __restrict__ Wbt,  // [4][col][k]
    const float* __restrict__ b1, const float* __restrict__ b2,
    const float* __restrict__ b3, const float* __restrict__ b4,
    float* __restrict__ x1, float* __restrict__ x3,
    __hip_bfloat16* __restrict__ g, int N)
{
    __shared__ __hip_bfloat16 Xs[128][136];   // row stride 272B -> 2-way (free)

    const int nodeBase = blockIdx.x * 128;
    const int tid      = threadIdx.x;

    // ---- stage X (fp32 -> bf16) ----
    {
        int r  = tid >> 1;            // 0..127
        int k0 = (tid & 1) * 64;
        int row = nodeBase + r;
        if (row >= N) row = N - 1;    // clamp; stores are guarded
        const float* src = X + (size_t)row * D + k0;
        #pragma unroll
        for (int i = 0; i < 8; ++i) {
            float4 u = *(const float4*)(src + i * 8);
            float4 v = *(const float4*)(src + i * 8 + 4);
            __hip_bfloat16 h[8];
            h[0] = __float2bfloat16(u.x); h[1] = __float2bfloat16(u.y);
            h[2] = __float2bfloat16(u.z); h[3] = __float2bfloat16(u.w);
            h[4] = __float2bfloat16(v.x); h[5] = __float2bfloat16(v.y);
            h[6] = __float2bfloat16(v.z); h[7] = __float2bfloat16(v.w);
            *(uint4*)&Xs[r][k0 + i * 8] = *(const uint4*)h;
        }
    }
    __syncthreads();

    const int wv   = tid >> 6;        // 0..3
    const int lane = tid & 63;
    const int wr   = (wv >> 1) * 64;
    const int wc   = (wv & 1) * 64;
    const int fr   = lane & 15;
    const int fq   = lane >> 4;

    // cache all A fragments (16 x ds_read_b128)
    bf16x8 a[4][4];                   // [kk][mf]
    #pragma unroll
    for (int kk = 0; kk < 4; ++kk)
        #pragma unroll
        for (int mf = 0; mf < 4; ++mf)
            a[kk][mf] = *(const bf16x8*)&Xs[wr + mf * 16 + fr][kk * 32 + fq * 8];

    #pragma unroll
    for (int m = 0; m < 4; ++m) {
        const __hip_bfloat16* Wm = Wbt + (size_t)m * D * D;
        f32x4 acc[4][4] = {};

        #pragma unroll
        for (int kk = 0; kk < 4; ++kk) {
            bf16x8 b[4];
            #pragma unroll
            for (int nf = 0; nf < 4; ++nf)
                b[nf] = *(const bf16x8*)(Wm + (size_t)(wc + nf * 16 + fr) * D
                                            + kk * 32 + fq * 8);
            #pragma unroll
            for (int mf = 0; mf < 4; ++mf)
                #pragma unroll
                for (int nf = 0; nf < 4; ++nf)
                    acc[mf][nf] = __builtin_amdgcn_mfma_f32_16x16x32_bf16(
                        a[kk][mf], b[nf], acc[mf][nf], 0, 0, 0);
        }

        const float* bias = (m == 0) ? b1 : (m == 1) ? b2 : (m == 2) ? b3 : b4;
        #pragma unroll
        for (int nf = 0; nf < 4; ++nf) {
            int col = wc + nf * 16 + fr;
            float bv = bias[col];
            #pragma unroll
            for (int mf = 0; mf < 4; ++mf) {
                #pragma unroll
                for (int j = 0; j < 4; ++j) {
                    int row = nodeBase + wr + mf * 16 + fq * 4 + j;
                    if (row < N) {
                        float v = acc[mf][nf][j] + bv;
                        if (m == 0)      x1[(size_t)row * D + col] = v;
                        else if (m == 2) x3[(size_t)row * D + col] = v;
                        else if (m == 1) g[(size_t)row * 256 + 128 + col] = __float2bfloat16(v);
                        else             g[(size_t)row * 256 + col]       = __float2bfloat16(v);
                    }
                }
            }
        }
    }
}

// ---------------------------------------------------------------------------
// Stage 2: CSR build by dst
// ---------------------------------------------------------------------------
__global__ void count_kernel(const int* __restrict__ dstIdx, int* __restrict__ cnt, int E)
{
    int e = blockIdx.x * 256 + threadIdx.x;
    if (e < E) atomicAdd(&cnt[dstIdx[e]], 1);
}

__global__ __launch_bounds__(256) void scan1(const int* __restrict__ cnt,
                                             int* __restrict__ row_off,
                                             int* __restrict__ bsum, int N)
{
    __shared__ int s[256];
    int tid = threadIdx.x;
    int i0  = blockIdx.x * 1024 + tid * 4;
    int v[4];
    #pragma unroll
    for (int j = 0; j < 4; ++j) v[j] = (i0 + j < N) ? cnt[i0 + j] : 0;
    int t = v[0] + v[1] + v[2] + v[3];
    s[tid] = t;
    __syncthreads();
    for (int off = 1; off < 256; off <<= 1) {
        int y = 0;
        if (tid >= off) y = s[tid - off];
        __syncthreads();
        s[tid] += y;
        __syncthreads();
    }
    int run = s[tid] - t;
    #pragma unroll
    for (int j = 0; j < 4; ++j) {
        if (i0 + j < N) row_off[i0 + j] = run;
        run += v[j];
    }
    if (tid == 255) bsum[blockIdx.x] = s[255];
}

__global__ void scan2(int* __restrict__ bsum, int nb)
{
    int lane = threadIdx.x;  // blockDim = 64
    int a = (lane < nb) ? bsum[lane] : 0;
    int b = (64 + lane < nb) ? bsum[64 + lane] : 0;
    int xa = a;
    #pragma unroll
    for (int off = 1; off < 64; off <<= 1) {
        int y = __shfl_up(xa, off);
        if (lane >= off) xa += y;
    }
    int totA = __shfl(xa, 63);
    int xb = b;
    #pragma unroll
    for (int off = 1; off < 64; off <<= 1) {
        int y = __shfl_up(xb, off);
        if (lane >= off) xb += y;
    }
    if (lane < nb) bsum[lane] = xa - a;
    if (64 + lane < nb) bsum[64 + lane] = totA + xb - b;
}

__global__ void scan3(int* __restrict__ row_off, const int* __restrict__ bsum, int N)
{
    int i = blockIdx.x * 256 + threadIdx.x;
    if (i < N) row_off[i] += bsum[i >> 10];
}

// fill: flatten indirection -> src_attr[pos] = {src, attr_bits}
__global__ void fill_kernel(const int* __restrict__ srcIdx,
                            const int* __restrict__ dstIdx,
                            const float* __restrict__ eattr,
                            const int* __restrict__ row_off,
                            int* __restrict__ cur,
                            int2* __restrict__ src_attr, int E)
{
    int e = blockIdx.x * 256 + threadIdx.x;
    if (e < E) {
        int d = dstIdx[e];
        int p = atomicAdd(&cur[d], 1);
        int2 rec;
        rec.x = srcIdx[e];
        rec.y = __float_as_int(eattr[e]);
        src_attr[row_off[d] + p] = rec;
    }
}

// ---------------------------------------------------------------------------
// Stage 3: per-dst-node attention + aggregation, one wave per node.
// Gathers come from packed bf16 record g[node][256] = x4 row | x2 row.
// Edge loop unrolled by 2 (overlapped gathers, one rescale per pair).
// ---------------------------------------------------------------------------
__global__ __launch_bounds__(256) void node_kernel(
    float* __restrict__ x1,                    // read x1, write node_out in place
    const unsigned* __restrict__ g,            // [node][128] uints (bf16 pairs)
    const float* __restrict__ x3,
    const float* __restrict__ W5,
    const float* __restrict__ b5,
    const int* __restrict__ row_off,
    const int* __restrict__ cnt,
    const int2* __restrict__ src_attr,
    int N)
{
    int n    = blockIdx.x * 4 + (threadIdx.x >> 6);
    int lane = threadIdx.x & 63;
    if (n >= N) return;

    const float2 a3 = *(const float2*)(x3 + (size_t)n * D + lane * 2);
    const float2 w5 = *(const float2*)(W5 + lane * 2);
    const float2 v5 = *(const float2*)(b5 + lane * 2);

    float p = a3.x * w5.x + a3.y * w5.y;
    float q = a3.x * v5.x + a3.y * v5.y;
    #pragma unroll
    for (int off = 32; off; off >>= 1) {
        p += __shfl_xor(p, off);
        q += __shfl_xor(q, off);
    }

    const int start = row_off[n];
    const int deg   = cnt[n];
    const float inv_sqrt_d = 0.08838834764831845f;  // 1/sqrt(128)

    float mrun = -INFINITY, z = 0.f;
    float accx = 0.f, accy = 0.f;

    int i = 0;
    for (; i + 2 <= deg; i += 2) {
        int2 r0 = src_attr[start + i];
        int2 r1 = src_attr[start + i + 1];
        const unsigned* g0 = g + (size_t)r0.x * 128;
        const unsigned* g1 = g + (size_t)r1.x * 128;
        unsigned u40 = g0[lane];
        unsigned u41 = g1[lane];
        unsigned u20 = g0[64 + lane];
        unsigned u21 = g1[64 + lane];

        float d0 = a3.x * bflo(u40) + a3.y * bfhi(u40);
        float d1 = a3.x * bflo(u41) + a3.y * bfhi(u41);
        #pragma unroll
        for (int off = 32; off; off >>= 1) {
            d0 += __shfl_xor(d0, off);
            d1 += __shfl_xor(d1, off);
        }
        float s0 = (d0 + __int_as_float(r0.y) * p + q) * inv_sqrt_d;
        float s1 = (d1 + __int_as_float(r1.y) * p + q) * inv_sqrt_d;

        float mn = fmaxf(mrun, fmaxf(s0, s1));
        float sc = __expf(mrun - mn);            // 0 on first pair
        float w0 = __expf(s0 - mn);
        float w1 = __expf(s1 - mn);
        z    = z    * sc + w0 + w1;
        accx = accx * sc + w0 * bflo(u20) + w1 * bflo(u21);
        accy = accy * sc + w0 * bfhi(u20) + w1 * bfhi(u21);
        mrun = mn;
    }
    if (i < deg) {
        int2 r0 = src_attr[start + i];
        const unsigned* g0 = g + (size_t)r0.x * 128;
        unsigned u40 = g0[lane];
        unsigned u20 = g0[64 + lane];
        float d0 = a3.x * bflo(u40) + a3.y * bfhi(u40);
        #pragma unroll
        for (int off = 32; off; off >>= 1) d0 += __shfl_xor(d0, off);
        float s0 = (d0 + __int_as_float(r0.y) * p + q) * inv_sqrt_d;
        float mn = fmaxf(mrun, s0);
        float sc = __expf(mrun - mn);
        float w0 = __expf(s0 - mn);
        z    = z    * sc + w0;
        accx = accx * sc + w0 * bflo(u20);
        accy = accy * sc + w0 * bfhi(u20);
        mrun = mn;
    }

    float2 o = *(const float2*)(x1 + (size_t)n * D + lane * 2);
    if (deg > 0) {
        float inv = 1.f / z;
        o.x += accx * inv;
        o.y += accy * inv;
    }
    *(float2*)(x1 + (size_t)n * D + lane * 2) = o;
}

// ---------------------------------------------------------------------------
// Stage 4: global mean pool (batch sorted -> register accumulate, few atomics)
// ---------------------------------------------------------------------------
__global__ __launch_bounds__(256) void pool_kernel(
    const float* __restrict__ node_out,
    const int* __restrict__ batch,
    float* __restrict__ pooled,
    float* __restrict__ cntf,
    int N)
{
    int c   = threadIdx.x & 127;
    int sub = threadIdx.x >> 7;  // 0..1
    int nodesPerBlock = (N + gridDim.x - 1) / gridDim.x;
    int startN = blockIdx.x * nodesPerBlock;
    int endN   = min(startN + nodesPerBlock, N);

    float acc = 0.f, cct = 0.f;
    int gcur = -1;
    for (int n = startN + sub; n < endN; n += 2) {
        int gg = batch[n];
        float v = node_out[(size_t)n * D + c];
        if (gg != gcur) {
            if (gcur >= 0) {
                atomicAdd(&pooled[gcur * D + c], acc);
                if (c == 0) atomicAdd(&cntf[gcur], cct);
            }
            gcur = gg; acc = 0.f; cct = 0.f;
        }
        acc += v; cct += 1.f;
    }
    if (gcur >= 0) {
        atomicAdd(&pooled[gcur * D + c], acc);
        if (c == 0) atomicAdd(&cntf[gcur], cct);
    }
}

__global__ void final_kernel(const float* __restrict__ pooled,
                             const float* __restrict__ cntf,
                             float* __restrict__ out)
{
    int i = blockIdx.x * 256 + threadIdx.x;
    if (i < NGRAPH * D) {
        float cval = cntf[i >> 7];
        out[i] = pooled[i] / fmaxf(cval, 1.f);
    }
}

// ---------------------------------------------------------------------------
extern "C" void kernel_launch(void* const* d_in, const int* in_sizes, int n_in,
                              void* d_out, int out_size, void* d_ws, size_t ws_size,
                              hipStream_t stream)
{
    const float* x     = (const float*)d_in[0];
    const int*   eidx  = (const int*)d_in[1];   // [2,E]: src = eidx[e], dst = eidx[E+e]
    const float* eattr = (const float*)d_in[2];
    const int*   batch = (const int*)d_in[3];
    const float* W1 = (const float*)d_in[4];  const float* b1 = (const float*)d_in[5];
    const float* W2 = (const float*)d_in[6];  const float* b2 = (const float*)d_in[7];
    const float* W3 = (const float*)d_in[8];  const float* b3 = (const float*)d_in[9];
    const float* W4 = (const float*)d_in[10]; const float* b4 = (const float*)d_in[11];
    const float* W5 = (const float*)d_in[12]; const float* b5 = (const float*)d_in[13];
    float* out = (float*)d_out;

    const int N = in_sizes[0] / D;
    const int E = in_sizes[1] / 2;

    // workspace layout
    char* ws = (char*)d_ws;
    size_t NB = (size_t)N * D * sizeof(float);      // 51.2 MB
    float* x1 = (float*)(ws + 0 * NB);              // also node_out (in place)
    float* x3 = (float*)(ws + 1 * NB);
    __hip_bfloat16* g = (__hip_bfloat16*)(ws + 2 * NB);  // [N][256] bf16 = NB bytes
    int* cnt      = (int*)(ws + 3 * NB);
    int* row_off  = cnt + N;
    int* cur      = row_off + N;
    int2* src_attr = (int2*)(cur + N + (N & 1));
    int* bsum     = (int*)(src_attr + E);
    float* pooled = (float*)(bsum + 256);
    float* cntf   = pooled + NGRAPH * D;
    __hip_bfloat16* Wbt = (__hip_bfloat16*)(cntf + NGRAPH);

    hipMemsetAsync(cnt, 0, (size_t)N * sizeof(int), stream);
    hipMemsetAsync(cur, 0, (size_t)N * sizeof(int), stream);
    hipMemsetAsync(pooled, 0, (size_t)(NGRAPH * D + NGRAPH) * sizeof(float), stream);

    wconv_kernel<<<(4 * D * D + 255) / 256, 256, 0, stream>>>(W1, W2, W3, W4, Wbt);

    proj3_kernel<<<(N + 127) / 128, 256, 0, stream>>>(x, Wbt, b1, b2, b3, b4,
                                                      x1, x3, g, N);

    count_kernel<<<(E + 255) / 256, 256, 0, stream>>>(eidx + E, cnt, E);
    int nb = (N + 1023) / 1024;
    scan1<<<nb, 256, 0, stream>>>(cnt, row_off, bsum, N);
    scan2<<<1, 64, 0, stream>>>(bsum, nb);
    scan3<<<(N + 255) / 256, 256, 0, stream>>>(row_off, bsum, N);
    fill_kernel<<<(E + 255) / 256, 256, 0, stream>>>(eidx, eidx + E, eattr,
                                                     row_off, cur, src_attr, E);

    node_kernel<<<(N + 3) / 4, 256, 0, stream>>>(x1, (const unsigned*)g, x3,
                                                 W5, b5, row_off, cnt, src_attr, N);

    pool_kernel<<<256, 256, 0, stream>>>(x1, batch, pooled, cntf, N);
    final_kernel<<<(NGRAPH * D + 255) / 256, 256, 0, stream>>>(pooled, cntf, out);
}

// Round 4
// 267.192 us; speedup vs baseline: 1.9768x; 1.1390x over previous
//
#include <hip/hip_runtime.h>
#include <hip/hip_bf16.h>
#include <math.h>

#define D 128
#define NGRAPH 16

typedef __attribute__((ext_vector_type(8))) short bf16x8;   // 8 bf16 (4 VGPRs)
typedef __attribute__((ext_vector_type(4))) float f32x4;    // MFMA C/D

// low-indexed / high-indexed bf16 of a packed pair -> f32
__device__ __forceinline__ float bflo(unsigned u) {
    union { unsigned i; float f; } v; v.i = u << 16; return v.f;
}
__device__ __forceinline__ float bfhi(unsigned u) {
    union { unsigned i; float f; } v; v.i = u & 0xffff0000u; return v.f;
}
__device__ __forceinline__ unsigned pack_bf16(float x, float y) {
    __hip_bfloat16 hx = __float2bfloat16(x);
    __hip_bfloat16 hy = __float2bfloat16(y);
    unsigned ux = *(const unsigned short*)&hx;
    unsigned uy = *(const unsigned short*)&hy;
    return ux | (uy << 16);
}

// ---------------------------------------------------------------------------
// Stage 0: convert W1..W4 to bf16, transposed to [m][col][k] (k contiguous)
// ---------------------------------------------------------------------------
__global__ void wconv_kernel(const float* __restrict__ W1, const float* __restrict__ W2,
                             const float* __restrict__ W3, const float* __restrict__ W4,
                             __hip_bfloat16* __restrict__ Wbt)
{
    int id = blockIdx.x * 256 + threadIdx.x;      // 4*128*128 = 65536
    if (id >= 4 * D * D) return;
    int mm  = id >> 14;
    int rem = id & 16383;
    int c   = rem >> 7;
    int k   = rem & 127;
    const float* Wm = (mm == 0) ? W1 : (mm == 1) ? W2 : (mm == 2) ? W3 : W4;
    Wbt[id] = __float2bfloat16(Wm[k * D + c]);
}

// ---------------------------------------------------------------------------
// Stage 1: all four projections, bf16 MFMA, bf16 outputs, coalesced epilogue.
// grid = ceil(N/128); 256 threads = 4 waves (2x2).
// Outputs (all bf16): x1b[N][128], x3b[N][128],
//                     gb[N][256] = x4 row (cols 0..127) | x2 row (128..255).
// Epilogue: acc -> Ls (reused X tile) -> uint4 row stores (256B/row).
// ---------------------------------------------------------------------------
__global__ __launch_bounds__(256) void proj4_kernel(
    const float* __restrict__ X,
    const __hip_bfloat16* __restrict__ Wbt,  // [4][col][k]
    const float* __restrict__ b1, const float* __restrict__ b2,
    const float* __restrict__ b3, const float* __restrict__ b4,
    unsigned short* __restrict__ x1b,
    unsigned short* __restrict__ x3b,
    unsigned short* __restrict__ gb, int N)
{
    __shared__ __hip_bfloat16 Ls[128][136];   // X stage, then repack buffer

    const int nodeBase = blockIdx.x * 128;
    const int tid      = threadIdx.x;

    // ---- stage X (fp32 -> bf16) ----
    {
        int r  = tid >> 1;            // 0..127
        int k0 = (tid & 1) * 64;
        int row = nodeBase + r;
        if (row >= N) row = N - 1;    // clamp; stores are guarded
        const float* src = X + (size_t)row * D + k0;
        #pragma unroll
        for (int i = 0; i < 8; ++i) {
            float4 u = *(const float4*)(src + i * 8);
            float4 v = *(const float4*)(src + i * 8 + 4);
            __hip_bfloat16 h[8];
            h[0] = __float2bfloat16(u.x); h[1] = __float2bfloat16(u.y);
            h[2] = __float2bfloat16(u.z); h[3] = __float2bfloat16(u.w);
            h[4] = __float2bfloat16(v.x); h[5] = __float2bfloat16(v.y);
            h[6] = __float2bfloat16(v.z); h[7] = __float2bfloat16(v.w);
            *(uint4*)&Ls[r][k0 + i * 8] = *(const uint4*)h;
        }
    }
    __syncthreads();

    const int wv   = tid >> 6;        // 0..3
    const int lane = tid & 63;
    const int wr   = (wv >> 1) * 64;
    const int wc   = (wv & 1) * 64;
    const int fr   = lane & 15;
    const int fq   = lane >> 4;

    // cache all A fragments (16 x ds_read_b128) -> Ls becomes reusable
    bf16x8 a[4][4];                   // [kk][mf]
    #pragma unroll
    for (int kk = 0; kk < 4; ++kk)
        #pragma unroll
        for (int mf = 0; mf < 4; ++mf)
            a[kk][mf] = *(const bf16x8*)&Ls[wr + mf * 16 + fr][kk * 32 + fq * 8];
    __syncthreads();

    #pragma unroll
    for (int m = 0; m < 4; ++m) {
        const __hip_bfloat16* Wm = Wbt + (size_t)m * D * D;
        f32x4 acc[4][4] = {};

        #pragma unroll
        for (int kk = 0; kk < 4; ++kk) {
            bf16x8 b[4];
            #pragma unroll
            for (int nf = 0; nf < 4; ++nf)
                b[nf] = *(const bf16x8*)(Wm + (size_t)(wc + nf * 16 + fr) * D
                                            + kk * 32 + fq * 8);
            #pragma unroll
            for (int mf = 0; mf < 4; ++mf)
                #pragma unroll
                for (int nf = 0; nf < 4; ++nf)
                    acc[mf][nf] = __builtin_amdgcn_mfma_f32_16x16x32_bf16(
                        a[kk][mf], b[nf], acc[mf][nf], 0, 0, 0);
        }

        // ---- bias + pack into Ls (C/D map: col=lane&15, row=(lane>>4)*4+j) ----
        const float* bias = (m == 0) ? b1 : (m == 1) ? b2 : (m == 2) ? b3 : b4;
        #pragma unroll
        for (int nf = 0; nf < 4; ++nf) {
            int col = wc + nf * 16 + fr;
            float bv = bias[col];
            #pragma unroll
            for (int mf = 0; mf < 4; ++mf)
                #pragma unroll
                for (int j = 0; j < 4; ++j)
                    Ls[wr + mf * 16 + fq * 4 + j][col] =
                        __float2bfloat16(acc[mf][nf][j] + bv);
        }
        __syncthreads();

        // ---- coalesced store: 2 threads per row, 128B each ----
        {
            int r    = tid >> 1;
            int half = tid & 1;
            int row  = nodeBase + r;
            if (row < N) {
                const uint4* s4 = (const uint4*)&Ls[r][half * 64];
                uint4* d4;
                if (m == 0)
                    d4 = (uint4*)(x1b + (size_t)row * 128 + half * 64);
                else if (m == 2)
                    d4 = (uint4*)(x3b + (size_t)row * 128 + half * 64);
                else if (m == 3)
                    d4 = (uint4*)(gb + (size_t)row * 256 + half * 64);
                else
                    d4 = (uint4*)(gb + (size_t)row * 256 + 128 + half * 64);
                #pragma unroll
                for (int i = 0; i < 8; ++i) d4[i] = s4[i];
            }
        }
        __syncthreads();
    }
}

// ---------------------------------------------------------------------------
// Stage 2: CSR build by dst
// ---------------------------------------------------------------------------
__global__ void count_kernel(const int* __restrict__ dstIdx, int* __restrict__ cnt, int E)
{
    int e = blockIdx.x * 256 + threadIdx.x;
    if (e < E) atomicAdd(&cnt[dstIdx[e]], 1);
}

__global__ __launch_bounds__(256) void scan1(const int* __restrict__ cnt,
                                             int* __restrict__ row_off,
                                             int* __restrict__ bsum, int N)
{
    __shared__ int s[256];
    int tid = threadIdx.x;
    int i0  = blockIdx.x * 1024 + tid * 4;
    int v[4];
    #pragma unroll
    for (int j = 0; j < 4; ++j) v[j] = (i0 + j < N) ? cnt[i0 + j] : 0;
    int t = v[0] + v[1] + v[2] + v[3];
    s[tid] = t;
    __syncthreads();
    for (int off = 1; off < 256; off <<= 1) {
        int y = 0;
        if (tid >= off) y = s[tid - off];
        __syncthreads();
        s[tid] += y;
        __syncthreads();
    }
    int run = s[tid] - t;
    #pragma unroll
    for (int j = 0; j < 4; ++j) {
        if (i0 + j < N) row_off[i0 + j] = run;
        run += v[j];
    }
    if (tid == 255) bsum[blockIdx.x] = s[255];
}

__global__ void scan2(int* __restrict__ bsum, int nb)
{
    int lane = threadIdx.x;  // blockDim = 64
    int a = (lane < nb) ? bsum[lane] : 0;
    int b = (64 + lane < nb) ? bsum[64 + lane] : 0;
    int xa = a;
    #pragma unroll
    for (int off = 1; off < 64; off <<= 1) {
        int y = __shfl_up(xa, off);
        if (lane >= off) xa += y;
    }
    int totA = __shfl(xa, 63);
    int xb = b;
    #pragma unroll
    for (int off = 1; off < 64; off <<= 1) {
        int y = __shfl_up(xb, off);
        if (lane >= off) xb += y;
    }
    if (lane < nb) bsum[lane] = xa - a;
    if (64 + lane < nb) bsum[64 + lane] = totA + xb - b;
}

__global__ void scan3(int* __restrict__ row_off, const int* __restrict__ bsum, int N)
{
    int i = blockIdx.x * 256 + threadIdx.x;
    if (i < N) row_off[i] += bsum[i >> 10];
}

// fill: flatten indirection -> src_attr[pos] = {src, attr_bits}
__global__ void fill_kernel(const int* __restrict__ srcIdx,
                            const int* __restrict__ dstIdx,
                            const float* __restrict__ eattr,
                            const int* __restrict__ row_off,
                            int* __restrict__ cur,
                            int2* __restrict__ src_attr, int E)
{
    int e = blockIdx.x * 256 + threadIdx.x;
    if (e < E) {
        int d = dstIdx[e];
        int p = atomicAdd(&cur[d], 1);
        int2 rec;
        rec.x = srcIdx[e];
        rec.y = __float_as_int(eattr[e]);
        src_attr[row_off[d] + p] = rec;
    }
}

// ---------------------------------------------------------------------------
// Stage 3: per-dst-node attention + aggregation, one wave per node.
// x3/x1 read as packed bf16; node_out written bf16 in place over x1b.
// ---------------------------------------------------------------------------
__global__ __launch_bounds__(256) void node_kernel(
    unsigned* __restrict__ x1b,                // bf16 pairs [N][64]; in/out
    const unsigned* __restrict__ g,            // [node][128] uints (bf16 pairs)
    const unsigned* __restrict__ x3b,          // bf16 pairs [N][64]
    const float* __restrict__ W5,
    const float* __restrict__ b5,
    const int* __restrict__ row_off,
    const int* __restrict__ cnt,
    const int2* __restrict__ src_attr,
    int N)
{
    int n    = blockIdx.x * 4 + (threadIdx.x >> 6);
    int lane = threadIdx.x & 63;
    if (n >= N) return;

    unsigned u3 = x3b[(size_t)n * 64 + lane];
    float a3x = bflo(u3), a3y = bfhi(u3);
    const float2 w5 = *(const float2*)(W5 + lane * 2);
    const float2 v5 = *(const float2*)(b5 + lane * 2);

    float p = a3x * w5.x + a3y * w5.y;
    float q = a3x * v5.x + a3y * v5.y;
    #pragma unroll
    for (int off = 32; off; off >>= 1) {
        p += __shfl_xor(p, off);
        q += __shfl_xor(q, off);
    }

    const int start = row_off[n];
    const int deg   = cnt[n];
    const float inv_sqrt_d = 0.08838834764831845f;  // 1/sqrt(128)

    float mrun = -INFINITY, z = 0.f;
    float accx = 0.f, accy = 0.f;

    int i = 0;
    for (; i + 2 <= deg; i += 2) {
        int2 r0 = src_attr[start + i];
        int2 r1 = src_attr[start + i + 1];
        const unsigned* g0 = g + (size_t)r0.x * 128;
        const unsigned* g1 = g + (size_t)r1.x * 128;
        unsigned u40 = g0[lane];
        unsigned u41 = g1[lane];
        unsigned u20 = g0[64 + lane];
        unsigned u21 = g1[64 + lane];

        float d0 = a3x * bflo(u40) + a3y * bfhi(u40);
        float d1 = a3x * bflo(u41) + a3y * bfhi(u41);
        #pragma unroll
        for (int off = 32; off; off >>= 1) {
            d0 += __shfl_xor(d0, off);
            d1 += __shfl_xor(d1, off);
        }
        float s0 = (d0 + __int_as_float(r0.y) * p + q) * inv_sqrt_d;
        float s1 = (d1 + __int_as_float(r1.y) * p + q) * inv_sqrt_d;

        float mn = fmaxf(mrun, fmaxf(s0, s1));
        float sc = __expf(mrun - mn);            // 0 on first pair
        float w0 = __expf(s0 - mn);
        float w1 = __expf(s1 - mn);
        z    = z    * sc + w0 + w1;
        accx = accx * sc + w0 * bflo(u20) + w1 * bflo(u21);
        accy = accy * sc + w0 * bfhi(u20) + w1 * bfhi(u21);
        mrun = mn;
    }
    if (i < deg) {
        int2 r0 = src_attr[start + i];
        const unsigned* g0 = g + (size_t)r0.x * 128;
        unsigned u40 = g0[lane];
        unsigned u20 = g0[64 + lane];
        float d0 = a3x * bflo(u40) + a3y * bfhi(u40);
        #pragma unroll
        for (int off = 32; off; off >>= 1) d0 += __shfl_xor(d0, off);
        float s0 = (d0 + __int_as_float(r0.y) * p + q) * inv_sqrt_d;
        float mn = fmaxf(mrun, s0);
        float sc = __expf(mrun - mn);
        float w0 = __expf(s0 - mn);
        z    = z    * sc + w0;
        accx = accx * sc + w0 * bflo(u20);
        accy = accy * sc + w0 * bfhi(u20);
        mrun = mn;
    }

    unsigned u1 = x1b[(size_t)n * 64 + lane];
    float ox = bflo(u1), oy = bfhi(u1);
    if (deg > 0) {
        float inv = 1.f / z;
        ox += accx * inv;
        oy += accy * inv;
    }
    x1b[(size_t)n * 64 + lane] = pack_bf16(ox, oy);
}

// ---------------------------------------------------------------------------
// Stage 4: global mean pool over bf16 node_out (batch sorted -> register
// accumulate, flush on graph change). 256 threads = 4 nodes x 64 uint cols.
// ---------------------------------------------------------------------------
__global__ __launch_bounds__(256) void pool_kernel(
    const unsigned* __restrict__ node_out,     // bf16 pairs [N][64]
    const int* __restrict__ batch,
    float* __restrict__ pooled,
    float* __restrict__ cntf,
    int N)
{
    int c   = threadIdx.x & 63;
    int sub = threadIdx.x >> 6;  // 0..3
    int nodesPerBlock = (N + gridDim.x - 1) / gridDim.x;
    int startN = blockIdx.x * nodesPerBlock;
    int endN   = min(startN + nodesPerBlock, N);

    float ax = 0.f, ay = 0.f, cct = 0.f;
    int gcur = -1;
    for (int n = startN + sub; n < endN; n += 4) {
        int gg = batch[n];
        unsigned u = node_out[(size_t)n * 64 + c];
        if (gg != gcur) {
            if (gcur >= 0) {
                atomicAdd(&pooled[gcur * D + c * 2], ax);
                atomicAdd(&pooled[gcur * D + c * 2 + 1], ay);
                if (c == 0) atomicAdd(&cntf[gcur], cct);
            }
            gcur = gg; ax = 0.f; ay = 0.f; cct = 0.f;
        }
        ax += bflo(u); ay += bfhi(u); cct += 1.f;
    }
    if (gcur >= 0) {
        atomicAdd(&pooled[gcur * D + c * 2], ax);
        atomicAdd(&pooled[gcur * D + c * 2 + 1], ay);
        if (c == 0) atomicAdd(&cntf[gcur], cct);
    }
}

__global__ void final_kernel(const float* __restrict__ pooled,
                             const float* __restrict__ cntf,
                             float* __restrict__ out)
{
    int i = blockIdx.x * 256 + threadIdx.x;
    if (i < NGRAPH * D) {
        float cval = cntf[i >> 7];
        out[i] = pooled[i] / fmaxf(cval, 1.f);
    }
}

// ---------------------------------------------------------------------------
extern "C" void kernel_launch(void* const* d_in, const int* in_sizes, int n_in,
                              void* d_out, int out_size, void* d_ws, size_t ws_size,
                              hipStream_t stream)
{
    const float* x     = (const float*)d_in[0];
    const int*   eidx  = (const int*)d_in[1];   // [2,E]: src = eidx[e], dst = eidx[E+e]
    const float* eattr = (const float*)d_in[2];
    const int*   batch = (const int*)d_in[3];
    const float* W1 = (const float*)d_in[4];  const float* b1 = (const float*)d_in[5];
    const float* W2 = (const float*)d_in[6];  const float* b2 = (const float*)d_in[7];
    const float* W3 = (const float*)d_in[8];  const float* b3 = (const float*)d_in[9];
    const float* W4 = (const float*)d_in[10]; const float* b4 = (const float*)d_in[11];
    const float* W5 = (const float*)d_in[12]; const float* b5 = (const float*)d_in[13];
    float* out = (float*)d_out;

    const int N = in_sizes[0] / D;
    const int E = in_sizes[1] / 2;

    // workspace layout (all bf16 node tensors)
    char* ws = (char*)d_ws;
    unsigned short* x1b = (unsigned short*)ws;              // [N][128] bf16
    unsigned short* x3b = x1b + (size_t)N * 128;            // [N][128] bf16
    unsigned short* gb  = x3b + (size_t)N * 128;            // [N][256] bf16
    int* cnt      = (int*)(gb + (size_t)N * 256);
    int* row_off  = cnt + N;
    int* cur      = row_off + N;
    int2* src_attr = (int2*)(cur + N + (N & 1));
    int* bsum     = (int*)(src_attr + E);
    float* pooled = (float*)(bsum + 256);
    float* cntf   = pooled + NGRAPH * D;
    __hip_bfloat16* Wbt = (__hip_bfloat16*)(((uintptr_t)(cntf + NGRAPH) + 15) & ~(uintptr_t)15);

    hipMemsetAsync(cnt, 0, (size_t)N * sizeof(int), stream);
    hipMemsetAsync(cur, 0, (size_t)N * sizeof(int), stream);
    hipMemsetAsync(pooled, 0, (size_t)(NGRAPH * D + NGRAPH) * sizeof(float), stream);

    wconv_kernel<<<(4 * D * D + 255) / 256, 256, 0, stream>>>(W1, W2, W3, W4, Wbt);

    proj4_kernel<<<(N + 127) / 128, 256, 0, stream>>>(x, Wbt, b1, b2, b3, b4,
                                                      x1b, x3b, gb, N);

    count_kernel<<<(E + 255) / 256, 256, 0, stream>>>(eidx + E, cnt, E);
    int nb = (N + 1023) / 1024;
    scan1<<<nb, 256, 0, stream>>>(cnt, row_off, bsum, N);
    scan2<<<1, 64, 0, stream>>>(bsum, nb);
    scan3<<<(N + 255) / 256, 256, 0, stream>>>(row_off, bsum, N);
    fill_kernel<<<(E + 255) / 256, 256, 0, stream>>>(eidx, eidx + E, eattr,
                                                     row_off, cur, src_attr, E);

    node_kernel<<<(N + 3) / 4, 256, 0, stream>>>((unsigned*)x1b, (const unsigned*)gb,
                                                 (const unsigned*)x3b,
                                                 W5, b5, row_off, cnt, src_attr, N);

    pool_kernel<<<256, 256, 0, stream>>>((const unsigned*)x1b, batch, pooled, cntf, N);
    final_kernel<<<(NGRAPH * D + 255) / 256, 256, 0, stream>>>(pooled, cntf, out);
}

// Round 5
// 231.718 us; speedup vs baseline: 2.2794x; 1.1531x over previous
//
#include <hip/hip_runtime.h>
#include <hip/hip_bf16.h>
#include <math.h>

#define D 128
#define NGRAPH 16

typedef __attribute__((ext_vector_type(8))) short bf16x8;   // 8 bf16 (4 VGPRs)
typedef __attribute__((ext_vector_type(4))) float f32x4;    // MFMA C/D

// low-indexed / high-indexed bf16 of a packed pair -> f32
__device__ __forceinline__ float bflo(unsigned u) {
    union { unsigned i; float f; } v; v.i = u << 16; return v.f;
}
__device__ __forceinline__ float bfhi(unsigned u) {
    union { unsigned i; float f; } v; v.i = u & 0xffff0000u; return v.f;
}
__device__ __forceinline__ unsigned pack_bf16(float x, float y) {
    __hip_bfloat16 hx = __float2bfloat16(x);
    __hip_bfloat16 hy = __float2bfloat16(y);
    unsigned ux = *(const unsigned short*)&hx;
    unsigned uy = *(const unsigned short*)&hy;
    return ux | (uy << 16);
}

// ---------------------------------------------------------------------------
// Stage A: edge count by dst  +  W1..W4 -> bf16 [m][col][k] (merged kernels)
// grid = max(ceil(E/256), 256)
// ---------------------------------------------------------------------------
__global__ void count_wconv_kernel(const int* __restrict__ dstIdx,
                                   int* __restrict__ cnt, int E,
                                   const float* __restrict__ W1, const float* __restrict__ W2,
                                   const float* __restrict__ W3, const float* __restrict__ W4,
                                   __hip_bfloat16* __restrict__ Wbt)
{
    int id = blockIdx.x * 256 + threadIdx.x;
    if (id < E) atomicAdd(&cnt[dstIdx[id]], 1);
    if (id < 4 * D * D) {
        int mm  = id >> 14;
        int rem = id & 16383;
        int c   = rem >> 7;
        int k   = rem & 127;
        const float* Wm = (mm == 0) ? W1 : (mm == 1) ? W2 : (mm == 2) ? W3 : W4;
        Wbt[id] = __float2bfloat16(Wm[k * D + c]);
    }
}

// ---------------------------------------------------------------------------
// Stage B: all four projections, bf16 MFMA, barrier-free per-wave epilogue.
// grid = ceil(N/128); 256 threads = 4 waves (2x2), each owns a 64x64 quadrant.
// Epilogue: wave packs its own fragments into a wave-PRIVATE LDS region
// (reuses the dead X tile) -> no __syncthreads in the m-loop.
// Outputs (bf16): x1b[N][128], x3b[N][128], gb[N][256] = x4 row | x2 row.
// ---------------------------------------------------------------------------
__global__ __launch_bounds__(256) void proj5_kernel(
    const float* __restrict__ X,
    const __hip_bfloat16* __restrict__ Wbt,  // [4][col][k]
    const float* __restrict__ b1, const float* __restrict__ b2,
    const float* __restrict__ b3, const float* __restrict__ b4,
    unsigned short* __restrict__ x1b,
    unsigned short* __restrict__ x3b,
    unsigned short* __restrict__ gb, int N)
{
    __shared__ __hip_bfloat16 Ls[128][136];   // X stage, then 4 wave-private repack regions

    const int nodeBase = blockIdx.x * 128;
    const int tid      = threadIdx.x;

    // ---- stage X (fp32 -> bf16) ----
    {
        int r  = tid >> 1;            // 0..127
        int k0 = (tid & 1) * 64;
        int row = nodeBase + r;
        if (row >= N) row = N - 1;    // clamp; stores are guarded
        const float* src = X + (size_t)row * D + k0;
        #pragma unroll
        for (int i = 0; i < 8; ++i) {
            float4 u = *(const float4*)(src + i * 8);
            float4 v = *(const float4*)(src + i * 8 + 4);
            __hip_bfloat16 h[8];
            h[0] = __float2bfloat16(u.x); h[1] = __float2bfloat16(u.y);
            h[2] = __float2bfloat16(u.z); h[3] = __float2bfloat16(u.w);
            h[4] = __float2bfloat16(v.x); h[5] = __float2bfloat16(v.y);
            h[6] = __float2bfloat16(v.z); h[7] = __float2bfloat16(v.w);
            *(uint4*)&Ls[r][k0 + i * 8] = *(const uint4*)h;
        }
    }
    __syncthreads();

    const int wv   = tid >> 6;        // 0..3
    const int lane = tid & 63;
    const int wr   = (wv >> 1) * 64;
    const int wc   = (wv & 1) * 64;
    const int fr   = lane & 15;
    const int fq   = lane >> 4;

    // cache all A fragments -> Ls becomes dead
    bf16x8 a[4][4];                   // [kk][mf]
    #pragma unroll
    for (int kk = 0; kk < 4; ++kk)
        #pragma unroll
        for (int mf = 0; mf < 4; ++mf)
            a[kk][mf] = *(const bf16x8*)&Ls[wr + mf * 16 + fr][kk * 32 + fq * 8];
    __syncthreads();                  // everyone done reading Ls

    // wave-private repack region: [64 rows][68 cols] bf16 (4352 elems/wave)
    __hip_bfloat16* Rs = &Ls[0][0] + wv * 4352;

    #pragma unroll
    for (int m = 0; m < 4; ++m) {
        const __hip_bfloat16* Wm = Wbt + (size_t)m * D * D;
        f32x4 acc[4][4] = {};

        #pragma unroll
        for (int kk = 0; kk < 4; ++kk) {
            bf16x8 b[4];
            #pragma unroll
            for (int nf = 0; nf < 4; ++nf)
                b[nf] = *(const bf16x8*)(Wm + (size_t)(wc + nf * 16 + fr) * D
                                            + kk * 32 + fq * 8);
            #pragma unroll
            for (int mf = 0; mf < 4; ++mf)
                #pragma unroll
                for (int nf = 0; nf < 4; ++nf)
                    acc[mf][nf] = __builtin_amdgcn_mfma_f32_16x16x32_bf16(
                        a[kk][mf], b[nf], acc[mf][nf], 0, 0, 0);
        }

        // ---- bias + pack into wave-private Rs (no cross-wave dependency) ----
        const float* bias = (m == 0) ? b1 : (m == 1) ? b2 : (m == 2) ? b3 : b4;
        #pragma unroll
        for (int nf = 0; nf < 4; ++nf) {
            int col = nf * 16 + fr;           // local col 0..63
            float bv = bias[wc + col];
            #pragma unroll
            for (int mf = 0; mf < 4; ++mf)
                #pragma unroll
                for (int j = 0; j < 4; ++j)
                    Rs[(mf * 16 + fq * 4 + j) * 68 + col] =
                        __float2bfloat16(acc[mf][nf][j] + bv);
        }
        // wave-local LDS RAW: compiler inserts lgkmcnt wait, no barrier needed

        // ---- readback + coalesced store: 8 lanes/row, 128B contiguous/row ----
        #pragma unroll
        for (int pp = 0; pp < 8; ++pp) {
            int rl = pp * 8 + (lane >> 3);    // local row 0..63
            int cl = (lane & 7) * 8;          // local col, 8 bf16 = 16B
            uint2 lo = *(const uint2*)&Rs[rl * 68 + cl];
            uint2 hi = *(const uint2*)&Rs[rl * 68 + cl + 4];
            int row = nodeBase + wr + rl;
            if (row < N) {
                uint4 v; v.x = lo.x; v.y = lo.y; v.z = hi.x; v.w = hi.y;
                unsigned short* dst;
                if (m == 0)      dst = x1b + (size_t)row * 128 + wc + cl;
                else if (m == 2) dst = x3b + (size_t)row * 128 + wc + cl;
                else if (m == 3) dst = gb + (size_t)row * 256 + wc + cl;
                else             dst = gb + (size_t)row * 256 + 128 + wc + cl;
                *(uint4*)dst = v;
            }
        }
    }
}

// ---------------------------------------------------------------------------
// Stage C: block scan of cnt (1024 elems/block) + block-sum scan
// ---------------------------------------------------------------------------
__global__ __launch_bounds__(256) void scan1(const int* __restrict__ cnt,
                                             int* __restrict__ row_off,
                                             int* __restrict__ bsum, int N)
{
    __shared__ int s[256];
    int tid = threadIdx.x;
    int i0  = blockIdx.x * 1024 + tid * 4;
    int v[4];
    #pragma unroll
    for (int j = 0; j < 4; ++j) v[j] = (i0 + j < N) ? cnt[i0 + j] : 0;
    int t = v[0] + v[1] + v[2] + v[3];
    s[tid] = t;
    __syncthreads();
    for (int off = 1; off < 256; off <<= 1) {
        int y = 0;
        if (tid >= off) y = s[tid - off];
        __syncthreads();
        s[tid] += y;
        __syncthreads();
    }
    int run = s[tid] - t;
    #pragma unroll
    for (int j = 0; j < 4; ++j) {
        if (i0 + j < N) row_off[i0 + j] = run;
        run += v[j];
    }
    if (tid == 255) bsum[blockIdx.x] = s[255];
}

__global__ void scan2(int* __restrict__ bsum, int nb)
{
    int lane = threadIdx.x;  // blockDim = 64
    int a = (lane < nb) ? bsum[lane] : 0;
    int b = (64 + lane < nb) ? bsum[64 + lane] : 0;
    int xa = a;
    #pragma unroll
    for (int off = 1; off < 64; off <<= 1) {
        int y = __shfl_up(xa, off);
        if (lane >= off) xa += y;
    }
    int totA = __shfl(xa, 63);
    int xb = b;
    #pragma unroll
    for (int off = 1; off < 64; off <<= 1) {
        int y = __shfl_up(xb, off);
        if (lane >= off) xb += y;
    }
    if (lane < nb) bsum[lane] = xa - a;
    if (64 + lane < nb) bsum[64 + lane] = totA + xb - b;
}

// ---------------------------------------------------------------------------
// Stage D: fill. Uses row_off itself as the cursor (no `cur` array, no scan3):
//   pos = atomicAdd(&row_off[d],1) + bsum[d>>10]
// After this kernel row_off[d] = local_excl + cnt[d]; node kernel recovers
//   start = row_off[n] + bsum[n>>10] - cnt[n].
// ---------------------------------------------------------------------------
__global__ void fill_kernel(const int* __restrict__ srcIdx,
                            const int* __restrict__ dstIdx,
                            const float* __restrict__ eattr,
                            int* __restrict__ row_off,
                            const int* __restrict__ bsum,
                            int2* __restrict__ src_attr, int E)
{
    int e = blockIdx.x * 256 + threadIdx.x;
    if (e < E) {
        int d = dstIdx[e];
        int p = atomicAdd(&row_off[d], 1);
        int2 rec;
        rec.x = srcIdx[e];
        rec.y = __float_as_int(eattr[e]);
        src_attr[p + bsum[d >> 10]] = rec;
    }
}

// ---------------------------------------------------------------------------
// Stage E: per-dst-node attention + aggregation. One wave per node, but the
// wave is split into two 32-lane halves, each owning 2 of every 4 edges.
// Per lane: 4 bf16 cols. Reduce = 5 shfl within half + 1 cross-half exchange
// per 2 scores (3 shfl/edge vs 6 before). z/acc kept split per half,
// combined once at the end. Out written bf16 in place over x1b.
// ---------------------------------------------------------------------------
__global__ __launch_bounds__(256) void node_kernel(
    unsigned* __restrict__ x1b,                // bf16 pairs [N][64]; in/out
    const unsigned* __restrict__ g,            // [node][128] uints (bf16 pairs)
    const unsigned* __restrict__ x3b,          // bf16 pairs [N][64]
    const float* __restrict__ W5,
    const float* __restrict__ b5,
    const int* __restrict__ row_off,
    const int* __restrict__ cnt,
    const int* __restrict__ bsum,
    const int2* __restrict__ src_attr,
    int N)
{
    int n    = blockIdx.x * 4 + (threadIdx.x >> 6);
    int lane = threadIdx.x & 63;
    if (n >= N) return;
    int h  = lane >> 5;        // half: 0 or 1
    int l5 = lane & 31;

    // a3: cols 4*l5 .. 4*l5+3 (both halves hold the full row replicated)
    uint2 a3u = *(const uint2*)(x3b + (size_t)n * 64 + l5 * 2);
    float a0 = bflo(a3u.x), a1 = bfhi(a3u.x), a2 = bflo(a3u.y), a3v = bfhi(a3u.y);

    float4 w5 = *(const float4*)(W5 + l5 * 4);
    float4 v5 = *(const float4*)(b5 + l5 * 4);
    float p = a0 * w5.x + a1 * w5.y + a2 * w5.z + a3v * w5.w;
    float q = a0 * v5.x + a1 * v5.y + a2 * v5.z + a3v * v5.w;
    #pragma unroll
    for (int off = 16; off; off >>= 1) {
        p += __shfl_xor(p, off);
        q += __shfl_xor(q, off);
    }

    const int deg   = cnt[n];
    const int start = row_off[n] + bsum[n >> 10] - deg;
    const float inv_sqrt_d = 0.08838834764831845f;  // 1/sqrt(128)

    float mrun = -INFINITY, z = 0.f;
    float acc0 = 0.f, acc1 = 0.f, acc2 = 0.f, acc3 = 0.f;

    for (int i = 0; i < deg; i += 4) {
        int e0 = i + h;          // this half's edges: i+h and i+2+h
        int e1 = i + 2 + h;
        int c0 = min(e0, deg - 1);
        int c1 = min(e1, deg - 1);
        int2 r0 = src_attr[start + c0];
        int2 r1 = src_attr[start + c1];
        const unsigned* g0 = g + (size_t)r0.x * 128;
        const unsigned* g1 = g + (size_t)r1.x * 128;
        uint2 u40 = *(const uint2*)(g0 + l5 * 2);
        uint2 u41 = *(const uint2*)(g1 + l5 * 2);
        uint2 u20 = *(const uint2*)(g0 + 64 + l5 * 2);
        uint2 u21 = *(const uint2*)(g1 + 64 + l5 * 2);

        float d0 = a0 * bflo(u40.x) + a1 * bfhi(u40.x) + a2 * bflo(u40.y) + a3v * bfhi(u40.y);
        float d1 = a0 * bflo(u41.x) + a1 * bfhi(u41.x) + a2 * bflo(u41.y) + a3v * bfhi(u41.y);
        #pragma unroll
        for (int off = 16; off; off >>= 1) {
            d0 += __shfl_xor(d0, off);
            d1 += __shfl_xor(d1, off);
        }
        float s0 = (d0 + __int_as_float(r0.y) * p + q) * inv_sqrt_d;
        float s1 = (d1 + __int_as_float(r1.y) * p + q) * inv_sqrt_d;
        if (e0 >= deg) s0 = -INFINITY;
        if (e1 >= deg) s1 = -INFINITY;
        float so0 = __shfl_xor(s0, 32);
        float so1 = __shfl_xor(s1, 32);
        float mn = fmaxf(mrun, fmaxf(fmaxf(s0, s1), fmaxf(so0, so1)));
        float sc = __expf(mrun - mn);           // 0 on first iteration
        float w0 = __expf(s0 - mn);             // 0 for masked edges
        float w1 = __expf(s1 - mn);
        z    = z    * sc + w0 + w1;
        acc0 = acc0 * sc + w0 * bflo(u20.x) + w1 * bflo(u21.x);
        acc1 = acc1 * sc + w0 * bfhi(u20.x) + w1 * bfhi(u21.x);
        acc2 = acc2 * sc + w0 * bflo(u20.y) + w1 * bflo(u21.y);
        acc3 = acc3 * sc + w0 * bfhi(u20.y) + w1 * bfhi(u21.y);
        mrun = mn;
    }

    // combine halves (mn was wave-uniform, so plain sums are valid)
    z    += __shfl_xor(z, 32);
    acc0 += __shfl_xor(acc0, 32);
    acc1 += __shfl_xor(acc1, 32);
    acc2 += __shfl_xor(acc2, 32);
    acc3 += __shfl_xor(acc3, 32);

    if (h == 0) {
        uint2 u1 = *(const uint2*)(x1b + (size_t)n * 64 + l5 * 2);
        float o0 = bflo(u1.x), o1 = bfhi(u1.x), o2 = bflo(u1.y), o3 = bfhi(u1.y);
        if (deg > 0) {
            float inv = 1.f / z;
            o0 += acc0 * inv; o1 += acc1 * inv; o2 += acc2 * inv; o3 += acc3 * inv;
        }
        uint2 o; o.x = pack_bf16(o0, o1); o.y = pack_bf16(o2, o3);
        *(uint2*)(x1b + (size_t)n * 64 + l5 * 2) = o;
    }
}

// ---------------------------------------------------------------------------
// Stage F: global mean pool over bf16 node_out (batch sorted -> register
// accumulate, flush on graph change).
// ---------------------------------------------------------------------------
__global__ __launch_bounds__(256) void pool_kernel(
    const unsigned* __restrict__ node_out,     // bf16 pairs [N][64]
    const int* __restrict__ batch,
    float* __restrict__ pooled,
    float* __restrict__ cntf,
    int N)
{
    int c   = threadIdx.x & 63;
    int sub = threadIdx.x >> 6;  // 0..3
    int nodesPerBlock = (N + gridDim.x - 1) / gridDim.x;
    int startN = blockIdx.x * nodesPerBlock;
    int endN   = min(startN + nodesPerBlock, N);

    float ax = 0.f, ay = 0.f, cct = 0.f;
    int gcur = -1;
    for (int n = startN + sub; n < endN; n += 4) {
        int gg = batch[n];
        unsigned u = node_out[(size_t)n * 64 + c];
        if (gg != gcur) {
            if (gcur >= 0) {
                atomicAdd(&pooled[gcur * D + c * 2], ax);
                atomicAdd(&pooled[gcur * D + c * 2 + 1], ay);
                if (c == 0) atomicAdd(&cntf[gcur], cct);
            }
            gcur = gg; ax = 0.f; ay = 0.f; cct = 0.f;
        }
        ax += bflo(u); ay += bfhi(u); cct += 1.f;
    }
    if (gcur >= 0) {
        atomicAdd(&pooled[gcur * D + c * 2], ax);
        atomicAdd(&pooled[gcur * D + c * 2 + 1], ay);
        if (c == 0) atomicAdd(&cntf[gcur], cct);
    }
}

__global__ void final_kernel(const float* __restrict__ pooled,
                             const float* __restrict__ cntf,
                             float* __restrict__ out)
{
    int i = blockIdx.x * 256 + threadIdx.x;
    if (i < NGRAPH * D) {
        float cval = cntf[i >> 7];
        out[i] = pooled[i] / fmaxf(cval, 1.f);
    }
}

// ---------------------------------------------------------------------------
extern "C" void kernel_launch(void* const* d_in, const int* in_sizes, int n_in,
                              void* d_out, int out_size, void* d_ws, size_t ws_size,
                              hipStream_t stream)
{
    const float* x     = (const float*)d_in[0];
    const int*   eidx  = (const int*)d_in[1];   // [2,E]: src = eidx[e], dst = eidx[E+e]
    const float* eattr = (const float*)d_in[2];
    const int*   batch = (const int*)d_in[3];
    const float* W1 = (const float*)d_in[4];  const float* b1 = (const float*)d_in[5];
    const float* W2 = (const float*)d_in[6];  const float* b2 = (const float*)d_in[7];
    const float* W3 = (const float*)d_in[8];  const float* b3 = (const float*)d_in[9];
    const float* W4 = (const float*)d_in[10]; const float* b4 = (const float*)d_in[11];
    const float* W5 = (const float*)d_in[12]; const float* b5 = (const float*)d_in[13];
    float* out = (float*)d_out;

    const int N = in_sizes[0] / D;
    const int E = in_sizes[1] / 2;

    // workspace layout (all bf16 node tensors)
    char* ws = (char*)d_ws;
    unsigned short* x1b = (unsigned short*)ws;              // [N][128] bf16
    unsigned short* x3b = x1b + (size_t)N * 128;            // [N][128] bf16
    unsigned short* gb  = x3b + (size_t)N * 128;            // [N][256] bf16
    int* cnt      = (int*)(gb + (size_t)N * 256);
    int* row_off  = cnt + N;
    int2* src_attr = (int2*)(row_off + N);                  // 2N ints before -> 8B aligned
    int* bsum     = (int*)(src_attr + E);
    float* pooled = (float*)(bsum + 256);
    float* cntf   = pooled + NGRAPH * D;
    __hip_bfloat16* Wbt = (__hip_bfloat16*)(((uintptr_t)(cntf + NGRAPH) + 15) & ~(uintptr_t)15);

    hipMemsetAsync(cnt, 0, (size_t)N * sizeof(int), stream);
    hipMemsetAsync(pooled, 0, (size_t)(NGRAPH * D + NGRAPH) * sizeof(float), stream);

    int cblocks = (E + 255) / 256;
    int wblocks = (4 * D * D + 255) / 256;
    count_wconv_kernel<<<(cblocks > wblocks ? cblocks : wblocks), 256, 0, stream>>>(
        eidx + E, cnt, E, W1, W2, W3, W4, Wbt);

    int nb = (N + 1023) / 1024;
    scan1<<<nb, 256, 0, stream>>>(cnt, row_off, bsum, N);
    scan2<<<1, 64, 0, stream>>>(bsum, nb);
    fill_kernel<<<(E + 255) / 256, 256, 0, stream>>>(eidx, eidx + E, eattr,
                                                     row_off, bsum, src_attr, E);

    proj5_kernel<<<(N + 127) / 128, 256, 0, stream>>>(x, Wbt, b1, b2, b3, b4,
                                                      x1b, x3b, gb, N);

    node_kernel<<<(N + 3) / 4, 256, 0, stream>>>((unsigned*)x1b, (const unsigned*)gb,
                                                 (const unsigned*)x3b,
                                                 W5, b5, row_off, cnt, bsum, src_attr, N);

    pool_kernel<<<256, 256, 0, stream>>>((const unsigned*)x1b, batch, pooled, cntf, N);
    final_kernel<<<(NGRAPH * D + 255) / 256, 256, 0, stream>>>(pooled, cntf, out);
}